// Round 7
// baseline (615.165 us; speedup 1.0000x reference)
//
#include <hip/hip_runtime.h>

namespace {
constexpr int kS   = 1024;
constexpr int kD   = 512;
constexpr int kH   = 8;
constexpr int kDFF = 2048;
constexpr int kNF  = 85;   // D//6
}

typedef __attribute__((ext_vector_type(8))) short bhalf8_t;    // 8x16-bit in 4 VGPRs
typedef _Float16 half8_t __attribute__((ext_vector_type(8)));
typedef __attribute__((ext_vector_type(4))) float f32x4_t;

// ---------------- helpers ----------------
__device__ __forceinline__ float wave_sum(float v) {
#pragma unroll
    for (int o = 1; o < 64; o <<= 1) v += __shfl_xor(v, o, 64);
    return v;
}
__device__ __forceinline__ unsigned short f2bf(float f) {   // RNE fp32->bf16
    unsigned u = __float_as_uint(f);
    u = (u + 0x7FFF + ((u >> 16) & 1)) >> 16;
    return (unsigned short)u;
}
__device__ __forceinline__ float bf2f(unsigned short h) {
    return __uint_as_float(((unsigned)h) << 16);
}
__device__ __forceinline__ unsigned short f2h(float f) {    // RNE fp32->fp16
    _Float16 h = (_Float16)f;
    return __builtin_bit_cast(unsigned short, h);
}

// ---------------- input projection + positional encoding ----------------
__global__ __launch_bounds__(256)
void input_pe_k(const float* __restrict__ feat, const float* __restrict__ pos,
                const float* __restrict__ fb, const float* __restrict__ in_w,
                const float* __restrict__ in_b, float* __restrict__ x)
{
    int s = blockIdx.x;
    int t = threadIdx.x;
    __shared__ float f[64];
    if (t < 64) f[t] = feat[s * 64 + t];
    __syncthreads();
    float acc0 = in_b[t], acc1 = in_b[t + 256];
#pragma unroll 8
    for (int c = 0; c < 64; ++c) {
        float fv = f[c];
        acc0 = fmaf(fv, in_w[c * kD + t], acc0);
        acc1 = fmaf(fv, in_w[c * kD + 256 + t], acc1);
    }
    float pe0 = 0.f, pe1 = 0.f;
    {
        int d = t;
        if (d < 6 * kNF) {
            int seg = d / kNF, idx = d - seg * kNF;
            float cs = pos[s * 3 + (seg >> 1)] * fb[idx];
            pe0 = (seg & 1) ? cosf(cs) : sinf(cs);
        }
        d = t + 256;
        if (d < 6 * kNF) {
            int seg = d / kNF, idx = d - seg * kNF;
            float cs = pos[s * 3 + (seg >> 1)] * fb[idx];
            pe1 = (seg & 1) ? cosf(cs) : sinf(cs);
        }
    }
    x[s * kD + t]       = acc0 + pe0;
    x[s * kD + 256 + t] = acc1 + pe1;
}

// ---------------- pairwise distance matrix ----------------
__global__ __launch_bounds__(256)
void dist_k(const float* __restrict__ pos, float* __restrict__ dist)
{
    int i = blockIdx.x;
    float px = pos[i * 3], py = pos[i * 3 + 1], pz = pos[i * 3 + 2];
    for (int j = threadIdx.x; j < kS; j += 256) {
        float dx = px - pos[j * 3], dy = py - pos[j * 3 + 1], dz = pz - pos[j * 3 + 2];
        float sq = dx * dx + dy * dy + dz * dz;
        dist[(long)i * kS + j] = sq > 0.f ? sqrtf(sq) : 0.f;
    }
}

// ---------------- exact PWL factorization of the distance-bias MLP ----------------
__global__ __launch_bounds__(256)
void pwl_build_k(const float* __restrict__ a_, const float* __restrict__ b_,
                 const float* __restrict__ w2, const float* __restrict__ b2,
                 float* __restrict__ bp_out, float* __restrict__ Atab, float* __restrict__ Btab)
{
    int l = blockIdx.x;
    a_ += l * 128; b_ += l * 128; w2 += l * 1024; b2 += l * 8;
    bp_out += l * 128; Atab += l * 1040; Btab += l * 1040;

    __shared__ float key[128], av[128], bv[128], sw2[1024], sb2[8];
    int t = threadIdx.x;
    for (int i = t; i < 1024; i += 256) sw2[i] = w2[i];
    if (t < 8) sb2[t] = b2[t];
    if (t < 128) {
        float a = a_[t], b = b_[t];
        av[t] = a; bv[t] = b;
        key[t] = (a != 0.f) ? (-b / a) : 3.0e38f;
    }
    __syncthreads();
    for (int ksz = 2; ksz <= 128; ksz <<= 1) {
        for (int j = ksz >> 1; j > 0; j >>= 1) {
            if (t < 128) {
                int ixj = t ^ j;
                if (ixj > t) {
                    bool up = ((t & ksz) == 0);
                    float x0 = key[t], x1 = key[ixj];
                    if ((x0 > x1) == up) { key[t] = x1; key[ixj] = x0; }
                }
            }
            __syncthreads();
        }
    }
    if (t < 128) bp_out[t] = key[t];
    __syncthreads();
    for (int task = t; task < 129 * 8; task += 256) {
        int seg = task >> 3, h = task & 7;
        float m;
        if (seg == 0)        m = key[0] - 1.0f;
        else if (seg == 128) m = key[127] + 1.0f;
        else                 m = 0.5f * (key[seg - 1] + key[seg]);
        float A = 0.f, B = 0.f;
        for (int c = 0; c < 128; ++c) {
            float a = av[c], b = bv[c];
            if (fmaf(a, m, b) > 0.f) {
                float w = sw2[c * 8 + h];
                A = fmaf(a, w, A);
                B = fmaf(b, w, B);
            }
        }
        Atab[seg * 8 + h] = A;
        Btab[seg * 8 + h] = B + sb2[h];
    }
}

// ---------------- fp32 -> bf16 3-term split, row-major (order0 [hi|lo|hi]) ------
__global__ __launch_bounds__(256)
void split3_rm_k(const float* __restrict__ in, unsigned short* __restrict__ out,
                 int total, int kshift, int ldin)
{
    long i = ((long)blockIdx.x * 256 + threadIdx.x) * 4;
    if (i >= total) return;
    int K = 1 << kshift;
    int m = (int)(i >> kshift), k = (int)(i & (K - 1));
    float4 v = *reinterpret_cast<const float4*>(in + (long)m * ldin + k);
    unsigned short h[4], lo[4];
    float fv[4] = {v.x, v.y, v.z, v.w};
#pragma unroll
    for (int j = 0; j < 4; ++j) {
        h[j] = f2bf(fv[j]);
        lo[j] = f2bf(fv[j] - bf2f(h[j]));
    }
    unsigned short* op = out + (long)m * (3 * K) + k;
    ushort4 hv = make_ushort4(h[0], h[1], h[2], h[3]);
    *reinterpret_cast<ushort4*>(op)         = hv;
    *reinterpret_cast<ushort4*>(op + K)     = make_ushort4(lo[0], lo[1], lo[2], lo[3]);
    *reinterpret_cast<ushort4*>(op + 2 * K) = hv;
}

// ---------------- fp32 K x N -> bf16 N x 3K transpose-split (weights, [hi|hi|lo]) --
__global__ __launch_bounds__(256)
void split3_tr_k(const float* __restrict__ in, unsigned short* __restrict__ out,
                 int K, int N, long szIn, long szOut)
{
    __shared__ float tile[32][33];
    int z = blockIdx.z;
    in  += (long)z * szIn;
    out += (long)z * szOut;
    int k0 = blockIdx.x * 32, n0 = blockIdx.y * 32;
    int t = threadIdx.x;
    int r = t >> 3, c4 = (t & 7) * 4;
    float4 v = *reinterpret_cast<const float4*>(&in[(long)(k0 + r) * N + n0 + c4]);
    tile[r][c4] = v.x; tile[r][c4 + 1] = v.y; tile[r][c4 + 2] = v.z; tile[r][c4 + 3] = v.w;
    __syncthreads();
    int nr = t >> 3, kq = (t & 7) * 4;
    unsigned short h[4], lo[4];
#pragma unroll
    for (int j = 0; j < 4; ++j) {
        float f = tile[kq + j][nr];
        h[j] = f2bf(f);
        lo[j] = f2bf(f - bf2f(h[j]));
    }
    unsigned short* op = out + (long)(n0 + nr) * (3 * K) + k0 + kq;
    ushort4 hv = make_ushort4(h[0], h[1], h[2], h[3]);
    *reinterpret_cast<ushort4*>(op)         = hv;
    *reinterpret_cast<ushort4*>(op + K)     = hv;
    *reinterpret_cast<ushort4*>(op + 2 * K) = make_ushort4(lo[0], lo[1], lo[2], lo[3]);
}

// ---------------- fp32 K x N -> f16 N x K transpose with scale (V matrix) -------
__global__ __launch_bounds__(256)
void tr_f16_k(const float* __restrict__ in, unsigned short* __restrict__ out,
              int K, int N, float scl)
{
    __shared__ float tile[32][33];
    int k0 = blockIdx.x * 32, n0 = blockIdx.y * 32;
    int t = threadIdx.x;
    int r = t >> 3, c4 = (t & 7) * 4;
    float4 v = *reinterpret_cast<const float4*>(&in[(long)(k0 + r) * N + n0 + c4]);
    tile[r][c4] = v.x; tile[r][c4 + 1] = v.y; tile[r][c4 + 2] = v.z; tile[r][c4 + 3] = v.w;
    __syncthreads();
    int nr = t >> 3, kq = (t & 7) * 4;
    unsigned short h[4];
#pragma unroll
    for (int j = 0; j < 4; ++j) h[j] = f2h(tile[kq + j][nr] * scl);
    *reinterpret_cast<ushort4*>(&out[(long)(n0 + nr) * K + k0 + kq]) =
        make_ushort4(h[0], h[1], h[2], h[3]);
}

// ---------------- 16-bit MFMA GEMM (bf16), split-K partial writer ----------------
// A: M x K row-major (lda), B: N x K row-major (ldb) — B pre-transposed.
// Tile 128x128, 4 waves of 64x64. K = slice len, bz = z*splitk+ks,
// partial -> Cpart[bz][M][N].
__global__ __launch_bounds__(256, 2)
void bgemm_k(const unsigned short* __restrict__ A,
             const unsigned short* __restrict__ B0, const unsigned short* __restrict__ B1,
             const unsigned short* __restrict__ B2,
             int M, int N, int K, int lda, int ldb,
             long sA, int splitk,
             float* __restrict__ Cpart)
{
    constexpr int BKp = 40;
    int tid = threadIdx.x;
    int bz = blockIdx.z;
    int z  = bz / splitk;
    int ks = bz - z * splitk;

    const unsigned short* Ap = A + (long)z * sA + (long)ks * K;
    const unsigned short* Bp = ((z == 1) ? B1 : (z == 2) ? B2 : B0) + (long)ks * K;

    __shared__ unsigned short As[128 * BKp];
    __shared__ unsigned short Bs[128 * BKp];

    int bm = blockIdx.x * 128;
    int bn = blockIdx.y * 128;
    int w = tid >> 6, lane = tid & 63, quad = lane >> 4, l16 = lane & 15;
    int wm = (w >> 1) * 64;
    int wn = (w & 1) * 64;

    int ar = tid >> 1, ac = (tid & 1) * 16;

    f32x4_t acc[4][4] = {};
    bhalf8_t aS0, aS1, bS0, bS1;

    auto ldgA = [&](int k0) {
        const unsigned short* p = Ap + (long)(bm + ar) * lda + k0 + ac;
        aS0 = *reinterpret_cast<const bhalf8_t*>(p);
        aS1 = *reinterpret_cast<const bhalf8_t*>(p + 8);
    };
    auto ldgB = [&](int k0) {
        const unsigned short* p = Bp + (long)(bn + ar) * ldb + k0 + ac;
        bS0 = *reinterpret_cast<const bhalf8_t*>(p);
        bS1 = *reinterpret_cast<const bhalf8_t*>(p + 8);
    };

    ldgA(0); ldgB(0);

    for (int k0 = 0; k0 < K; k0 += 32) {
        *reinterpret_cast<bhalf8_t*>(&As[ar * BKp + ac])     = aS0;
        *reinterpret_cast<bhalf8_t*>(&As[ar * BKp + ac + 8]) = aS1;
        *reinterpret_cast<bhalf8_t*>(&Bs[ar * BKp + ac])     = bS0;
        *reinterpret_cast<bhalf8_t*>(&Bs[ar * BKp + ac + 8]) = bS1;
        __syncthreads();
        if (k0 + 32 < K) { ldgA(k0 + 32); ldgB(k0 + 32); }
        bhalf8_t af[4], bf[4];
#pragma unroll
        for (int i = 0; i < 4; ++i)
            af[i] = *reinterpret_cast<const bhalf8_t*>(&As[(wm + i * 16 + l16) * BKp + quad * 8]);
#pragma unroll
        for (int j = 0; j < 4; ++j)
            bf[j] = *reinterpret_cast<const bhalf8_t*>(&Bs[(wn + j * 16 + l16) * BKp + quad * 8]);
#pragma unroll
        for (int i = 0; i < 4; ++i)
#pragma unroll
            for (int j = 0; j < 4; ++j)
                acc[i][j] = __builtin_amdgcn_mfma_f32_16x16x32_bf16(af[i], bf[j], acc[i][j], 0, 0, 0);
        __syncthreads();
    }

    float* Cp = Cpart + (long)bz * M * N;
#pragma unroll
    for (int i = 0; i < 4; ++i)
#pragma unroll
        for (int j = 0; j < 4; ++j)
#pragma unroll
            for (int r = 0; r < 4; ++r) {
                int m = bm + wm + i * 16 + quad * 4 + r;
                int n = bn + wn + j * 16 + l16;
                Cp[(long)m * N + n] = acc[i][j][r];
            }
}

// ---------------- fused flash attention (one head-block per 32 Q rows) ----------
// qb3/kb3: per-head 1024x192 (3-split, A/B orders). vtb: per-head 64x1024 f16 x1024.
// Output: aob 1024x1536 3-split bf16 [hi|lo|hi] over the 512 cols.
__global__ __launch_bounds__(256, 2)
void flash_k(const unsigned short* __restrict__ qb3, const unsigned short* __restrict__ kb3,
             const unsigned short* __restrict__ vtb, const float* __restrict__ dist,
             const float* __restrict__ bp, const float* __restrict__ Atab,
             const float* __restrict__ Btab, unsigned short* __restrict__ aob)
{
    __shared__ unsigned short Ks[128 * 200];
    __shared__ unsigned short Ps[32 * 136];
    __shared__ float bps_s[128], Ah[129], Bh[129];
    __shared__ float mrow[32], lrow[32], alph[32], mnw[32];
    __shared__ float pmax[4][32], psum[4][32];

    int tid = threadIdx.x;
    int h = blockIdx.y;
    int bm = blockIdx.x * 32;
    const unsigned short* Qh = qb3 + (long)h * 196608;
    const unsigned short* Kh = kb3 + (long)h * 196608;
    const unsigned short* Vh = vtb + (long)h * 65536;

    if (tid < 128) bps_s[tid] = bp[tid];
    if (tid < 129) { Ah[tid] = Atab[tid * 8 + h]; Bh[tid] = Btab[tid * 8 + h]; }
    if (tid < 32)  { mrow[tid] = -3.0e38f; lrow[tid] = 0.f; }

    int w = tid >> 6, lane = tid & 63, quad = lane >> 4, l16 = lane & 15;
    int wn = w * 32;

    // Q fragments: rows bm..bm+31, K=192
    bhalf8_t aq[2][6];
#pragma unroll
    for (int mb = 0; mb < 2; ++mb)
#pragma unroll
        for (int kq = 0; kq < 6; ++kq)
            aq[mb][kq] = *reinterpret_cast<const bhalf8_t*>(
                &Qh[(long)(bm + mb * 16 + l16) * 192 + kq * 32 + quad * 8]);

    f32x4_t oacc[2] = {};   // O rows mb*16+quad*4+r, col d = w*16+l16

    int r_st = tid >> 1;
    int c_st = (tid & 1) * 96;

    for (int nt = 0; nt < 8; ++nt) {
        int n0 = nt * 128;
        __syncthreads();            // Ks/Ps safe to overwrite
#pragma unroll
        for (int i = 0; i < 6; ++i) {
            int c = c_st + i * 16;
            // stage FULL 16 elements (two bhalf8) — round-6 bug was missing c+8..c+15
            *reinterpret_cast<bhalf8_t*>(&Ks[r_st * 200 + c]) =
                *reinterpret_cast<const bhalf8_t*>(&Kh[(long)(n0 + r_st) * 192 + c]);
            *reinterpret_cast<bhalf8_t*>(&Ks[r_st * 200 + c + 8]) =
                *reinterpret_cast<const bhalf8_t*>(&Kh[(long)(n0 + r_st) * 192 + c + 8]);
        }
        __syncthreads();

        f32x4_t sacc[2][2] = {};
#pragma unroll
        for (int kq = 0; kq < 6; ++kq) {
            bhalf8_t b0 = *reinterpret_cast<const bhalf8_t*>(&Ks[(wn + l16) * 200 + kq * 32 + quad * 8]);
            bhalf8_t b1 = *reinterpret_cast<const bhalf8_t*>(&Ks[(wn + 16 + l16) * 200 + kq * 32 + quad * 8]);
            sacc[0][0] = __builtin_amdgcn_mfma_f32_16x16x32_bf16(aq[0][kq], b0, sacc[0][0], 0, 0, 0);
            sacc[0][1] = __builtin_amdgcn_mfma_f32_16x16x32_bf16(aq[0][kq], b1, sacc[0][1], 0, 0, 0);
            sacc[1][0] = __builtin_amdgcn_mfma_f32_16x16x32_bf16(aq[1][kq], b0, sacc[1][0], 0, 0, 0);
            sacc[1][1] = __builtin_amdgcn_mfma_f32_16x16x32_bf16(aq[1][kq], b1, sacc[1][1], 0, 0, 0);
        }

        // scale + PWL bias
        float sv[2][2][4];
#pragma unroll
        for (int mb = 0; mb < 2; ++mb)
#pragma unroll
            for (int nb = 0; nb < 2; ++nb)
#pragma unroll
                for (int r = 0; r < 4; ++r) {
                    int gm = bm + mb * 16 + quad * 4 + r;
                    int gn = n0 + wn + nb * 16 + l16;
                    float t = dist[(long)gm * kS + gn];
                    int lo = 0, hi2 = 128;
                    while (lo < hi2) { int mid = (lo + hi2) >> 1; if (bps_s[mid] < t) lo = mid + 1; else hi2 = mid; }
                    sv[mb][nb][r] = fmaf(sacc[mb][nb][r], 0.125f, fmaf(Ah[lo], t, Bh[lo]));
                }

        // wave-local row max over 32 cols
        float ml[2][4];
#pragma unroll
        for (int mb = 0; mb < 2; ++mb)
#pragma unroll
            for (int r = 0; r < 4; ++r) {
                float m_ = fmaxf(sv[mb][0][r], sv[mb][1][r]);
#pragma unroll
                for (int off = 1; off < 16; off <<= 1) m_ = fmaxf(m_, __shfl_xor(m_, off, 64));
                ml[mb][r] = m_;
            }
        if (l16 == 0) {
#pragma unroll
            for (int mb = 0; mb < 2; ++mb)
#pragma unroll
                for (int r = 0; r < 4; ++r)
                    pmax[w][mb * 16 + quad * 4 + r] = ml[mb][r];
        }
        __syncthreads();
        if (tid < 32) {
            float mn_ = fmaxf(fmaxf(pmax[0][tid], pmax[1][tid]), fmaxf(pmax[2][tid], pmax[3][tid]));
            float mo  = mrow[tid];
            float m2  = fmaxf(mo, mn_);
            alph[tid] = __expf(mo - m2);
            mnw[tid]  = m2;
            mrow[tid] = m2;
        }
        __syncthreads();

        // P = exp(s - m), partial row sums, store P*2^14 as f16
        float sl[2][4];
#pragma unroll
        for (int mb = 0; mb < 2; ++mb)
#pragma unroll
            for (int r = 0; r < 4; ++r) {
                int m = mb * 16 + quad * 4 + r;
                float mN = mnw[m];
                float p0 = __expf(sv[mb][0][r] - mN);
                float p1 = __expf(sv[mb][1][r] - mN);
                Ps[m * 136 + wn + l16]      = f2h(p0 * 16384.f);
                Ps[m * 136 + wn + 16 + l16] = f2h(p1 * 16384.f);
                float s_ = p0 + p1;
#pragma unroll
                for (int off = 1; off < 16; off <<= 1) s_ += __shfl_xor(s_, off, 64);
                sl[mb][r] = s_;
            }
        if (l16 == 0) {
#pragma unroll
            for (int mb = 0; mb < 2; ++mb)
#pragma unroll
                for (int r = 0; r < 4; ++r)
                    psum[w][mb * 16 + quad * 4 + r] = sl[mb][r];
        }
        // rescale O-acc by alpha
#pragma unroll
        for (int mb = 0; mb < 2; ++mb)
#pragma unroll
            for (int r = 0; r < 4; ++r)
                oacc[mb][r] *= alph[mb * 16 + quad * 4 + r];
        __syncthreads();
        if (tid < 32)
            lrow[tid] = lrow[tid] * alph[tid] +
                        (psum[0][tid] + psum[1][tid] + psum[2][tid] + psum[3][tid]);

        // PV: O(32x64) += P(32x128) @ V^T-tile, f16 MFMA; V read from global (L2-hot)
#pragma unroll
        for (int kq2 = 0; kq2 < 4; ++kq2) {
            bhalf8_t bv = *reinterpret_cast<const bhalf8_t*>(
                &Vh[(long)(w * 16 + l16) * 1024 + n0 + kq2 * 32 + quad * 8]);
#pragma unroll
            for (int mb = 0; mb < 2; ++mb) {
                bhalf8_t ap = *reinterpret_cast<const bhalf8_t*>(
                    &Ps[(mb * 16 + l16) * 136 + kq2 * 32 + quad * 8]);
                oacc[mb] = __builtin_amdgcn_mfma_f32_16x16x32_f16(
                    __builtin_bit_cast(half8_t, ap), __builtin_bit_cast(half8_t, bv),
                    oacc[mb], 0, 0, 0);
            }
        }
    }
    __syncthreads();

    // epilogue: O / (2^24 * l), write aob 3-split (order0)
#pragma unroll
    for (int mb = 0; mb < 2; ++mb)
#pragma unroll
        for (int r = 0; r < 4; ++r) {
            int m = mb * 16 + quad * 4 + r;
            float val = oacc[mb][r] * ((1.f / 16777216.f) / lrow[m]);
            unsigned short hi = f2bf(val);
            unsigned short lo = f2bf(val - bf2f(hi));
            long base = (long)(bm + m) * 1536 + h * 64 + w * 16 + l16;
            aob[base]        = hi;
            aob[base + 512]  = lo;
            aob[base + 1024] = hi;
        }
}

// ---------------- QKV split-K reduce: bias + direct 3-split to qb3/kb3, v f32 ----
__global__ __launch_bounds__(256)
void reduce_qkv_k(const float* __restrict__ part,
                  unsigned short* __restrict__ qb3, unsigned short* __restrict__ kb3,
                  float* __restrict__ v,
                  const float* __restrict__ qbias, const float* __restrict__ kbias,
                  const float* __restrict__ vbias)
{
    int z = blockIdx.y;
    const long MN = (long)kS * kD;
    long idx = ((long)blockIdx.x * 256 + threadIdx.x) * 4;
    const float* pz = part + (long)z * 4 * MN + idx;
    float4 s = *reinterpret_cast<const float4*>(pz);
#pragma unroll
    for (int t = 1; t < 4; ++t) {
        float4 vv = *reinterpret_cast<const float4*>(pz + (long)t * MN);
        s.x += vv.x; s.y += vv.y; s.z += vv.z; s.w += vv.w;
    }
    int m = (int)(idx >> 9), n = (int)(idx & 511);
    const float* bzp = (z == 1) ? kbias : (z == 2) ? vbias : qbias;
    s.x += bzp[n]; s.y += bzp[n + 1]; s.z += bzp[n + 2]; s.w += bzp[n + 3];
    if (z == 2) {
        *reinterpret_cast<float4*>(v + idx) = s;
        return;
    }
    float fv[4] = {s.x, s.y, s.z, s.w};
    unsigned short h[4], lo[4];
#pragma unroll
    for (int j = 0; j < 4; ++j) {
        h[j] = f2bf(fv[j]);
        lo[j] = f2bf(fv[j] - bf2f(h[j]));
    }
    int head = n >> 6, hc = n & 63;
    unsigned short* dst = ((z == 1) ? kb3 : qb3) + (long)head * 196608 + (long)m * 192 + hc;
    ushort4 hv = make_ushort4(h[0], h[1], h[2], h[3]);
    ushort4 lv = make_ushort4(lo[0], lo[1], lo[2], lo[3]);
    *reinterpret_cast<ushort4*>(dst) = hv;
    if (z == 0) {  // A-side [hi|lo|hi]
        *reinterpret_cast<ushort4*>(dst + 64)  = lv;
        *reinterpret_cast<ushort4*>(dst + 128) = hv;
    } else {       // B-side [hi|hi|lo]
        *reinterpret_cast<ushort4*>(dst + 64)  = hv;
        *reinterpret_cast<ushort4*>(dst + 128) = lv;
    }
}

// ---------------- generic split-K reduce -> f32 (+bias) ----------------
__global__ __launch_bounds__(256)
void reduce_k(const float* __restrict__ part, float* __restrict__ C,
              const float* __restrict__ bias, int N, int splitk)
{
    const long MN = (long)kS * N;
    long idx = ((long)blockIdx.x * 256 + threadIdx.x) * 4;
    const float* pz = part + idx;
    float4 s = *reinterpret_cast<const float4*>(pz);
    for (int t = 1; t < splitk; ++t) {
        float4 v = *reinterpret_cast<const float4*>(pz + (long)t * MN);
        s.x += v.x; s.y += v.y; s.z += v.z; s.w += v.w;
    }
    int n = (int)(idx % N);
    s.x += bias[n]; s.y += bias[n + 1]; s.z += bias[n + 2]; s.w += bias[n + 3];
    *reinterpret_cast<float4*>(C + idx) = s;
}

// ---------------- FFN1 reduce: bias + relu + direct 3-split to hb ----------------
__global__ __launch_bounds__(256)
void reduce3_k(const float* __restrict__ part, unsigned short* __restrict__ hb,
               const float* __restrict__ bias, int splitk)
{
    const long MN = (long)kS * kDFF;
    long idx = ((long)blockIdx.x * 256 + threadIdx.x) * 4;
    const float* pz = part + idx;
    float4 s = *reinterpret_cast<const float4*>(pz);
    for (int t = 1; t < splitk; ++t) {
        float4 v = *reinterpret_cast<const float4*>(pz + (long)t * MN);
        s.x += v.x; s.y += v.y; s.z += v.z; s.w += v.w;
    }
    int m = (int)(idx >> 11), n = (int)(idx & 2047);
    float fv[4] = {fmaxf(s.x + bias[n], 0.f), fmaxf(s.y + bias[n + 1], 0.f),
                   fmaxf(s.z + bias[n + 2], 0.f), fmaxf(s.w + bias[n + 3], 0.f)};
    unsigned short h[4], lo[4];
#pragma unroll
    for (int j = 0; j < 4; ++j) {
        h[j] = f2bf(fv[j]);
        lo[j] = f2bf(fv[j] - bf2f(h[j]));
    }
    unsigned short* dst = hb + (long)m * 6144 + n;
    ushort4 hv = make_ushort4(h[0], h[1], h[2], h[3]);
    *reinterpret_cast<ushort4*>(dst)        = hv;
    *reinterpret_cast<ushort4*>(dst + 2048) = make_ushort4(lo[0], lo[1], lo[2], lo[3]);
    *reinterpret_cast<ushort4*>(dst + 4096) = hv;
}

// ---------------- residual add + layernorm (in place on x, + 3-split xb) --------
__global__ __launch_bounds__(256)
void add_ln_k(float* __restrict__ x, const float* __restrict__ y,
              const float* __restrict__ g, const float* __restrict__ b,
              unsigned short* __restrict__ xb)
{
    __shared__ float sm[4];
    int row = blockIdx.x, t = threadIdx.x;
    float* xr = x + (long)row * kD;
    const float* yr = y + (long)row * kD;
    float s0 = xr[t] + yr[t];
    float s1 = xr[t + 256] + yr[t + 256];
    float sum = wave_sum(s0 + s1);
    if ((t & 63) == 0) sm[t >> 6] = sum;
    __syncthreads();
    sum = sm[0] + sm[1] + sm[2] + sm[3];
    float mu = sum * (1.f / kD);
    float d0 = s0 - mu, d1 = s1 - mu;
    __syncthreads();
    float vs = wave_sum(d0 * d0 + d1 * d1);
    if ((t & 63) == 0) sm[t >> 6] = vs;
    __syncthreads();
    vs = sm[0] + sm[1] + sm[2] + sm[3];
    float rs = rsqrtf(vs * (1.f / kD) + 1e-5f);
    float o0 = fmaf(d0 * rs, g[t], b[t]);
    float o1 = fmaf(d1 * rs, g[t + 256], b[t + 256]);
    xr[t]       = o0;
    xr[t + 256] = o1;
    unsigned short h0 = f2bf(o0), l0 = f2bf(o0 - bf2f(h0));
    unsigned short h1 = f2bf(o1), l1 = f2bf(o1 - bf2f(h1));
    unsigned short* xrow = xb + (long)row * 1536;
    xrow[t]            = h0;  xrow[t + 256]        = h1;
    xrow[t + 512]      = l0;  xrow[t + 768]        = l1;
    xrow[t + 1024]     = h0;  xrow[t + 1280]       = h1;
}

// ---------------- mean-pool partials ----------------
__global__ __launch_bounds__(256)
void pool_k(const float* __restrict__ x, float* __restrict__ partial)
{
    int col = blockIdx.x * 256 + threadIdx.x;
    int rb = blockIdx.y;
    float s = 0.f;
    for (int r = rb * 128; r < rb * 128 + 128; ++r) s += x[(long)r * kD + col];
    partial[rb * kD + col] = s;
}

// ---------------- classifier head ----------------
__global__ __launch_bounds__(256)
void head_k(const float* __restrict__ partial,
            const float* __restrict__ c1w, const float* __restrict__ c1b,
            const float* __restrict__ c2w, const float* __restrict__ c2b,
            float* __restrict__ out)
{
    __shared__ float pooled[kD];
    __shared__ float h1[256];
    int t = threadIdx.x;
    for (int d = t; d < kD; d += 256) {
        float s = 0.f;
        for (int r = 0; r < 8; ++r) s += partial[r * kD + d];
        pooled[d] = s * (1.0f / kS);
    }
    __syncthreads();
    float acc = c1b[t];
    for (int f = 0; f < kD; ++f) acc = fmaf(pooled[f], c1w[f * 256 + t], acc);
    h1[t] = fmaxf(acc, 0.f);
    __syncthreads();
    if (t < 10) {
        float o = c2b[t];
        for (int f = 0; f < 256; ++f) o = fmaf(h1[f], c2w[f * 10 + t], o);
        out[t] = o;
    }
}

// ---------------- launch ----------------
extern "C" void kernel_launch(void* const* d_in, const int* in_sizes, int n_in,
                              void* d_out, int out_size, void* d_ws, size_t ws_size,
                              hipStream_t stream)
{
    (void)in_sizes; (void)n_in; (void)out_size; (void)ws_size;
    const float* features = (const float*)d_in[0];
    const float* positions= (const float*)d_in[1];
    const float* fb       = (const float*)d_in[2];
    const float* in_w     = (const float*)d_in[3];
    const float* in_b     = (const float*)d_in[4];
    const float* qw  = (const float*)d_in[5];
    const float* qb  = (const float*)d_in[6];
    const float* kw  = (const float*)d_in[7];
    const float* kb  = (const float*)d_in[8];
    const float* vw  = (const float*)d_in[9];
    const float* vb  = (const float*)d_in[10];
    const float* ow  = (const float*)d_in[11];
    const float* ob  = (const float*)d_in[12];
    const float* db1w= (const float*)d_in[13];
    const float* db1b= (const float*)d_in[14];
    const float* db2w= (const float*)d_in[15];
    const float* db2b= (const float*)d_in[16];
    const float* n1g = (const float*)d_in[17];
    const float* n1b = (const float*)d_in[18];
    const float* n2g = (const float*)d_in[19];
    const float* n2b = (const float*)d_in[20];
    const float* f1w = (const float*)d_in[21];
    const float* f1b = (const float*)d_in[22];
    const float* f2w = (const float*)d_in[23];
    const float* f2b = (const float*)d_in[24];
    const float* c1w = (const float*)d_in[25];
    const float* c1b = (const float*)d_in[26];
    const float* c2w = (const float*)d_in[27];
    const float* c2b = (const float*)d_in[28];

    float* ws = (float*)d_ws;
    const long SD = (long)kS * kD;            // 524288
    float* x      = ws;
    float* v      = ws + 1 * SD;
    float* y      = ws + 2 * SD;
    float* dist   = ws + 3 * SD;              // 2*SD
    float* part   = ws + 5 * SD;              // up to 12*SD (QKV partials)
    float* bpw    = ws + 17 * SD;
    float* Atab   = bpw + 256;
    float* Btab   = Atab + 2080;
    float* partial= Btab + 2080;

    unsigned short* ub = (unsigned short*)(ws + 17 * SD + 8512);
    unsigned short* xb   = ub;                       // 1024*1536
    unsigned short* aob  = xb   + 1572864;           // 1024*1536
    unsigned short* qb3  = aob  + 1572864;           // 8*1024*192
    unsigned short* kb3  = qb3  + 1572864;
    unsigned short* vtb  = kb3  + 1572864;           // 512*1024 (f16)
    unsigned short* hb   = vtb  + 524288;            // 1024*6144
    unsigned short* qwb  = hb   + 6291456;           // 2 x 512*1536
    unsigned short* kwb  = qwb  + 1572864;
    unsigned short* vwb  = kwb  + 1572864;
    unsigned short* owb  = vwb  + 1572864;
    unsigned short* f1wb = owb  + 1572864;           // 2 x 2048*1536
    unsigned short* f2wb = f1wb + 6291456;           // 2 x 512*6144

    input_pe_k<<<kS, 256, 0, stream>>>(features, positions, fb, in_w, in_b, x);
    dist_k<<<kS, 256, 0, stream>>>(positions, dist);
    pwl_build_k<<<2, 256, 0, stream>>>(db1w, db1b, db2w, db2b, bpw, Atab, Btab);
    split3_rm_k<<<512, 256, 0, stream>>>(x, xb, 524288, 9, 512);

    split3_tr_k<<<dim3(16, 16, 2), 256, 0, stream>>>(qw, qwb, 512, 512, 262144, 786432);
    split3_tr_k<<<dim3(16, 16, 2), 256, 0, stream>>>(kw, kwb, 512, 512, 262144, 786432);
    split3_tr_k<<<dim3(16, 16, 2), 256, 0, stream>>>(vw, vwb, 512, 512, 262144, 786432);
    split3_tr_k<<<dim3(16, 16, 2), 256, 0, stream>>>(ow, owb, 512, 512, 262144, 786432);
    split3_tr_k<<<dim3(16, 64, 2), 256, 0, stream>>>(f1w, f1wb, 512, 2048, 1048576, 3145728);
    split3_tr_k<<<dim3(64, 16, 2), 256, 0, stream>>>(f2w, f2wb, 2048, 512, 1048576, 3145728);

    for (int l = 0; l < 2; ++l) {
        // QKV: A=xb (1024x1536), split-K x4 -> partials; reduce fuses bias + q/k 3-split
        bgemm_k<<<dim3(8, 4, 12), 256, 0, stream>>>(
            xb, qwb + l * 786432, kwb + l * 786432, vwb + l * 786432,
            1024, 512, 384, 1536, 1536, 0, 4, part);
        reduce_qkv_k<<<dim3(512, 3), 256, 0, stream>>>(
            part, qb3, kb3, v, qb + l * kD, kb + l * kD, vb + l * kD);
        tr_f16_k<<<dim3(32, 16), 256, 0, stream>>>(v, vtb, 1024, 512, 1024.f);

        // fused attention -> aob (3-split)
        flash_k<<<dim3(32, 8), 256, 0, stream>>>(
            qb3, kb3, vtb, dist, bpw + l * 128, Atab + l * 1040, Btab + l * 1040, aob);

        // O-proj: split-K x8
        bgemm_k<<<dim3(8, 4, 8), 256, 0, stream>>>(
            aob, owb + l * 786432, owb + l * 786432, owb + l * 786432,
            1024, 512, 192, 1536, 1536, 0, 8, part);
        reduce_k<<<512, 256, 0, stream>>>(part, y, ob + l * kD, 512, 8);
        add_ln_k<<<kS, 256, 0, stream>>>(x, y, n1g + l * kD, n1b + l * kD, xb);

        // FFN1: split-K x2, reduce fuses bias+relu+3-split -> hb
        bgemm_k<<<dim3(8, 16, 2), 256, 0, stream>>>(
            xb, f1wb + l * 3145728, f1wb + l * 3145728, f1wb + l * 3145728,
            1024, 2048, 768, 1536, 1536, 0, 2, part);
        reduce3_k<<<2048, 256, 0, stream>>>(part, hb, f1b + l * kDFF, 2);

        // FFN2: split-K x8
        bgemm_k<<<dim3(8, 4, 8), 256, 0, stream>>>(
            hb, f2wb + l * 3145728, f2wb + l * 3145728, f2wb + l * 3145728,
            1024, 512, 768, 6144, 6144, 0, 8, part);
        reduce_k<<<512, 256, 0, stream>>>(part, y, f2b + l * kD, 512, 8);
        add_ln_k<<<kS, 256, 0, stream>>>(x, y, n2g + l * kD, n2b + l * kD, xb);
    }

    pool_k<<<dim3(2, 8), 256, 0, stream>>>(x, partial);
    head_k<<<1, 256, 0, stream>>>(partial, c1w, c1b, c2w, c2b, (float*)d_out);
}